// Round 9
// baseline (210.997 us; speedup 1.0000x reference)
//
#include <hip/hip_runtime.h>
#include <hip/hip_bf16.h>

// GAT layer: N=4096, F_IN=128, F_OUT=64, HEADS=4.
// R9 (= R8 with compile fix: nontemporal loads via ext-vector f32x4, not
// HIP_vector_type float4).
//  - XCD-clustered 1D grid: id&7 -> (head, col-half); with round-robin
//    block->XCD dispatch, all 64 blocks sharing an H-slice live on one XCD.
//  - 256-thr blocks, 128-col LDS chunks -> 17.3 KB LDS -> 8 blocks/CU.
//  - cg split 2 (Hpart 8.4 MB) + nontemporal stores (no write-allocate).
//  - Hrow fp32 for gat_fin's diagonal term (coalesced).
// Kernels: pack_bits -> gat_prep -> gat_main -> gat_fin.

#define NN 4096
#define FIN 128
#define FOUT 64
#define NH 4

typedef __attribute__((ext_vector_type(8))) short bf16x8;
typedef __attribute__((ext_vector_type(4))) float f32x4;
typedef __attribute__((ext_vector_type(4))) unsigned int u32x4;

__device__ __forceinline__ unsigned short f32_bf16(float f) {
    unsigned u = __builtin_bit_cast(unsigned, f);
    u += 0x7fffu + ((u >> 16) & 1u);          // round-to-nearest-even
    return (unsigned short)(u >> 16);
}

// ---------------- Kernel 0: pack A (int32 0/1) into bitmask ----------------
// grid 4096 blocks x 256 thr; block = one row, 16 column chunks. nt loads.
__global__ __launch_bounds__(256) void pack_bits(
    const int* __restrict__ A, unsigned long long* __restrict__ Abits)
{
    const int row  = blockIdx.x;
    const int lane = threadIdx.x & 63;
    const int wv   = threadIdx.x >> 6;
    const int* arow = A + (size_t)row * NN;
    #pragma unroll 4
    for (int c = 0; c < 16; ++c) {
        const int col = c * 256 + wv * 64 + lane;
        unsigned long long m = __ballot(__builtin_nontemporal_load(&arow[col]) > 0);
        if (lane == 0) Abits[(size_t)row * 64 + c * 4 + wv] = m;
    }
}

// ---------------- Kernel 1: prep ----------------
// H = X@W[h]^T + b (fp32). Outputs: bf16 H^T [h][o][n], fp32 Hrow [h][n][o],
// s,d and factored exponentials es=e^s, es2=e^{0.01s}, ed=e^d, ed2=e^{0.01d}.
__global__ __launch_bounds__(256) void gat_prep(
    const float* __restrict__ X, const float* __restrict__ W,
    const float* __restrict__ b, const float* __restrict__ att,
    unsigned short* __restrict__ HbfT, float* __restrict__ Hrow,
    float* __restrict__ s_out, float* __restrict__ d_out,
    float* __restrict__ es_g, float* __restrict__ es2_g,
    float* __restrict__ ed_g, float* __restrict__ ed2_g)
{
    const int rb = blockIdx.x;           // 0..127
    const int h  = blockIdx.y;           // 0..3
    const int n0 = rb * 32;
    const int t  = threadIdx.x;          // 0..255

    __shared__ float Xl[32][132];
    __shared__ float Wt[128][68];

    for (int g = t; g < 32 * 32; g += 256) {
        int row = g >> 5, c4 = g & 31;
        float4 v = *(const float4*)&X[(size_t)(n0 + row) * FIN + c4 * 4];
        *(float4*)&Xl[row][c4 * 4] = v;
    }
    for (int g = t; g < 64 * 32; g += 256) {
        int o = g >> 5, c4 = g & 31;
        float4 v = *(const float4*)&W[((size_t)h * FOUT + o) * FIN + c4 * 4];
        Wt[c4 * 4 + 0][o] = v.x; Wt[c4 * 4 + 1][o] = v.y;
        Wt[c4 * 4 + 2][o] = v.z; Wt[c4 * 4 + 3][o] = v.w;
    }
    __syncthreads();

    const int rg = t >> 4;               // rows rg*2 .. rg*2+1
    const int og = t & 15;               // cols og*4 .. og*4+3
    float acc[2][4] = {};

    #pragma unroll 4
    for (int f4 = 0; f4 < 32; ++f4) {
        float xv[2][4], wv[4][4];
        #pragma unroll
        for (int i = 0; i < 2; ++i) {
            float4 tmp = *(const float4*)&Xl[rg * 2 + i][f4 * 4];
            xv[i][0] = tmp.x; xv[i][1] = tmp.y; xv[i][2] = tmp.z; xv[i][3] = tmp.w;
        }
        #pragma unroll
        for (int k = 0; k < 4; ++k) {
            float4 tmp = *(const float4*)&Wt[f4 * 4 + k][og * 4];
            wv[k][0] = tmp.x; wv[k][1] = tmp.y; wv[k][2] = tmp.z; wv[k][3] = tmp.w;
        }
        #pragma unroll
        for (int i = 0; i < 2; ++i)
            #pragma unroll
            for (int k = 0; k < 4; ++k)
                #pragma unroll
                for (int jj = 0; jj < 4; ++jj)
                    acc[i][jj] = fmaf(xv[i][k], wv[k][jj], acc[i][jj]);
    }

    float bb[4], as_[4], ad_[4];
    #pragma unroll
    for (int jj = 0; jj < 4; ++jj) {
        bb[jj]  = b[h * FOUT + og * 4 + jj];
        as_[jj] = att[h * 2 * FOUT + og * 4 + jj];
        ad_[jj] = att[h * 2 * FOUT + FOUT + og * 4 + jj];
    }
    #pragma unroll
    for (int i = 0; i < 2; ++i)
        #pragma unroll
        for (int jj = 0; jj < 4; ++jj)
            acc[i][jj] += bb[jj];

    float sp[2] = {0.f, 0.f}, dp[2] = {0.f, 0.f};
    #pragma unroll
    for (int i = 0; i < 2; ++i)
        #pragma unroll
        for (int jj = 0; jj < 4; ++jj) {
            sp[i] = fmaf(acc[i][jj], as_[jj], sp[i]);
            dp[i] = fmaf(acc[i][jj], ad_[jj], dp[i]);
        }
    #pragma unroll
    for (int off = 1; off < 16; off <<= 1) {
        #pragma unroll
        for (int i = 0; i < 2; ++i) {
            sp[i] += __shfl_xor(sp[i], off);
            dp[i] += __shfl_xor(dp[i], off);
        }
    }
    if (og == 0) {
        #pragma unroll
        for (int i = 0; i < 2; ++i) {
            int nn = n0 + rg * 2 + i;
            s_out[h * NN + nn]  = sp[i];
            d_out[h * NN + nn]  = dp[i];
            es_g [h * NN + nn]  = __expf(sp[i]);
            es2_g[h * NN + nn]  = __expf(0.01f * sp[i]);
            ed_g [h * NN + nn]  = __expf(dp[i]);
            ed2_g[h * NN + nn]  = __expf(0.01f * dp[i]);
        }
    }

    // fp32 row copy for gat_fin's diagonal term (coalesced there)
    #pragma unroll
    for (int i = 0; i < 2; ++i) {
        float4 v = make_float4(acc[i][0], acc[i][1], acc[i][2], acc[i][3]);
        *(float4*)&Hrow[((size_t)h * NN + n0 + rg * 2 + i) * FOUT + og * 4] = v;
    }
    #pragma unroll
    for (int jj = 0; jj < 4; ++jj) {
        int o = og * 4 + jj;
        ushort2 p;
        p.x = f32_bf16(acc[0][jj]);
        p.y = f32_bf16(acc[1][jj]);
        *(ushort2*)&HbfT[((size_t)h * FOUT + o) * NN + n0 + rg * 2] = p;
    }
}

// ---------------- Kernel 2: masked softmax-aggregate ------------------------
// 1D grid 512, XCD-clustered: (h,cg) = id&7, bx = id>>3 (64-row tiles).
// Block: 1 head x 64 rows x 2048 cols = 16 staged 128-col chunks; 4 waves.
__global__ __launch_bounds__(256, 8) void gat_main(
    const unsigned* __restrict__ Abits, const unsigned short* __restrict__ HbfT,
    const float* __restrict__ es_g, const float* __restrict__ es2_g,
    const float* __restrict__ ed_g, const float* __restrict__ ed2_g,
    float* __restrict__ Hpart, float* __restrict__ lpartP)
{
    const int id  = blockIdx.x;          // 0..511
    const int grp = id & 7;              // XCD-clustered group
    const int h   = grp >> 1;            // head
    const int cg  = grp & 1;             // col half: [cg*2048, +2048)
    const int bx  = id >> 3;             // 0..63 row tile
    const int n0  = bx * 64;
    const int tid  = threadIdx.x;
    const int w    = tid >> 6;           // wave 0..3 -> rows w*16..+16
    const int lane = tid & 63;
    const int r    = lane & 15;          // A row within subtile / C col
    const int q    = lane >> 4;          // quad
    const int qs   = q * 8;

    __shared__ unsigned short Hlds[64][128];     // 16 KB, XOR-swizzled 16B blocks
    __shared__ unsigned bits_lds[64 * 5];        // 1.25 KB (stride 5)

    const int n = n0 + w * 16 + r;
    const float es  = es_g [h * NN + n];
    const float es2 = es2_g[h * NN + n];
    const int bits_base = (w * 16 + r) * 5;

    bf16x8 ones;
    #pragma unroll
    for (int i = 0; i < 8; ++i) ones[i] = (short)0x3F80;   // bf16 1.0

    f32x4 acc0 = {0,0,0,0}, acc1 = {0,0,0,0}, acc2 = {0,0,0,0},
          acc3 = {0,0,0,0}, accl = {0,0,0,0};

    for (int ch = 0; ch < 16; ++ch) {
        const int c0 = cg * 2048 + ch * 128;
        __syncthreads();                 // previous chunk fully consumed

        // ---- stage H chunk: HbfT[h][o][c0..c0+128) -> Hlds[o][.], swizzled ----
        #pragma unroll
        for (int it = 0; it < 4; ++it) {
            int flat = it * 256 + tid;           // 0..1023 (16B blocks)
            int o    = flat >> 4;                // 0..63
            int c16  = flat & 15;
            int blk  = c16 ^ (o & 15);
            *(bf16x8*)&Hlds[o][blk * 8] =
                *(const bf16x8*)&HbfT[((size_t)h * FOUT + o) * NN + c0 + c16 * 8];
        }
        // ---- stage adjacency bits: 64 rows x 4 u32 for this chunk ----
        {
            int row = tid >> 2, wd = tid & 3;
            bits_lds[row * 5 + wd] = Abits[(size_t)(n0 + row) * 128 + (c0 >> 5) + wd];
        }
        __syncthreads();

        const float* edh  = ed_g  + h * NN + c0;
        const float* ed2h = ed2_g + h * NN + c0;

        #pragma unroll
        for (int step = 0; step < 4; ++step) {
            const unsigned bits8 = bits_lds[bits_base + step] >> qs;
            const int mk = step * 32 + qs;

            const float4 e0 = *(const float4*)&edh [mk];
            const float4 e1 = *(const float4*)&edh [mk + 4];
            const float4 g0 = *(const float4*)&ed2h[mk];
            const float4 g1 = *(const float4*)&ed2h[mk + 4];
            const float edv [8] = {e0.x, e0.y, e0.z, e0.w, e1.x, e1.y, e1.z, e1.w};
            const float ed2v[8] = {g0.x, g0.y, g0.z, g0.w, g1.x, g1.y, g1.z, g1.w};

            u32x4 afu;
            #pragma unroll
            for (int p = 0; p < 4; ++p) {
                const int j0 = 2 * p, j1 = 2 * p + 1;
                float wa = (bits8 & (1u << j0))
                         ? fmaxf(es * edv[j0], es2 * ed2v[j0]) : 0.0f;
                float wb = (bits8 & (1u << j1))
                         ? fmaxf(es * edv[j1], es2 * ed2v[j1]) : 0.0f;
                __hip_bfloat162 pk = __float22bfloat162_rn(make_float2(wa, wb));
                unsigned u;
                __builtin_memcpy(&u, &pk, sizeof(u));   // v_cvt_pk path
                afu[p] = u;
            }
            const bf16x8 af = __builtin_bit_cast(bf16x8, afu);

            // B fragments from swizzled LDS ((r+16k)&15 == r for all four)
            const int mb = (step * 4 + q) ^ r;   // 16B-block index after swizzle
            const bf16x8 b0 = *(const bf16x8*)&Hlds[r     ][mb * 8];
            const bf16x8 b1 = *(const bf16x8*)&Hlds[r + 16][mb * 8];
            const bf16x8 b2 = *(const bf16x8*)&Hlds[r + 32][mb * 8];
            const bf16x8 b3 = *(const bf16x8*)&Hlds[r + 48][mb * 8];

            acc0 = __builtin_amdgcn_mfma_f32_16x16x32_bf16(af, b0,   acc0, 0, 0, 0);
            acc1 = __builtin_amdgcn_mfma_f32_16x16x32_bf16(af, b1,   acc1, 0, 0, 0);
            acc2 = __builtin_amdgcn_mfma_f32_16x16x32_bf16(af, b2,   acc2, 0, 0, 0);
            acc3 = __builtin_amdgcn_mfma_f32_16x16x32_bf16(af, b3,   acc3, 0, 0, 0);
            accl = __builtin_amdgcn_mfma_f32_16x16x32_bf16(af, ones, accl, 0, 0, 0);
        }
    }

    // ---- epilogue: nontemporal stores into this block's private slice ----
    float* hb = Hpart + ((size_t)(cg * NH + h) * NN + n0 + w * 16) * FOUT;
    #pragma unroll
    for (int reg = 0; reg < 4; ++reg) {
        const int rr = q * 4 + reg;
        __builtin_nontemporal_store(acc0[reg], &hb[rr * FOUT +  0 + r]);
        __builtin_nontemporal_store(acc1[reg], &hb[rr * FOUT + 16 + r]);
        __builtin_nontemporal_store(acc2[reg], &hb[rr * FOUT + 32 + r]);
        __builtin_nontemporal_store(acc3[reg], &hb[rr * FOUT + 48 + r]);
    }
    if (r == 0) {                        // col-0 lanes hold the 2048-col row-sums
        #pragma unroll
        for (int reg = 0; reg < 4; ++reg)
            __builtin_nontemporal_store(accl[reg],
                &lpartP[(size_t)(cg * NH + h) * NN + n0 + w * 16 + q * 4 + reg]);
    }
}

// ---------------- Kernel 3: finalize ----------------
// out[n][o] = sum_h (sum_cg Hpart + w_diag*Hrow) * 0.25/(sum_cg l + w_diag)
__global__ __launch_bounds__(256) void gat_fin(
    const float* __restrict__ Hpart, const float* __restrict__ Hrow,
    const float* __restrict__ lpartP, const float* __restrict__ s_g,
    const float* __restrict__ d_g, float* __restrict__ out)
{
    const int tid = threadIdx.x;
    const int rr  = tid >> 4;
    const int c4  = tid & 15;
    const int n   = blockIdx.x * 16 + rr;
    const int o   = c4 * 4;

    float4 res = make_float4(0.f, 0.f, 0.f, 0.f);
    #pragma unroll
    for (int h = 0; h < NH; ++h) {
        float l = lpartP[(size_t)h * NN + n]
                + lpartP[(size_t)(NH + h) * NN + n];
        float tt = s_g[h * NN + n] + d_g[h * NN + n];
        float wd = __expf(fmaxf(tt, 0.01f * tt));
        float inv = 0.25f / (l + wd);

        f32x4 h0 = __builtin_nontemporal_load(
            (const f32x4*)&Hpart[((size_t)h * NN + n) * FOUT + o]);
        f32x4 h1 = __builtin_nontemporal_load(
            (const f32x4*)&Hpart[((size_t)(NH + h) * NN + n) * FOUT + o]);
        float4 hr = *(const float4*)&Hrow[((size_t)h * NN + n) * FOUT + o];

        res.x += (h0[0] + h1[0] + wd * hr.x) * inv;
        res.y += (h0[1] + h1[1] + wd * hr.y) * inv;
        res.z += (h0[2] + h1[2] + wd * hr.z) * inv;
        res.w += (h0[3] + h1[3] + wd * hr.w) * inv;
    }
    *(float4*)&out[(size_t)n * FOUT + o] = res;
}

extern "C" void kernel_launch(void* const* d_in, const int* in_sizes, int n_in,
                              void* d_out, int out_size, void* d_ws, size_t ws_size,
                              hipStream_t stream) {
    const float* X   = (const float*)d_in[0];
    const int*   A   = (const int*)  d_in[1];
    const float* W   = (const float*)d_in[2];
    const float* b   = (const float*)d_in[3];
    const float* att = (const float*)d_in[4];
    float* out = (float*)d_out;

    char* ws = (char*)d_ws;
    unsigned short* HbfT = (unsigned short*)ws;                    // 2 MB
    size_t off = (size_t)NH * FOUT * NN * 2;
    float* s_buf   = (float*)(ws + off);  off += (size_t)NH * NN * 4;
    float* d_buf   = (float*)(ws + off);  off += (size_t)NH * NN * 4;
    float* es_buf  = (float*)(ws + off);  off += (size_t)NH * NN * 4;
    float* es2_buf = (float*)(ws + off);  off += (size_t)NH * NN * 4;
    float* ed_buf  = (float*)(ws + off);  off += (size_t)NH * NN * 4;
    float* ed2_buf = (float*)(ws + off);  off += (size_t)NH * NN * 4;
    unsigned long long* Abits = (unsigned long long*)(ws + off);
    off += (size_t)NN * 64 * 8;                                         // 2 MB
    float* Hrow   = (float*)(ws + off);
    off += (size_t)NH * NN * FOUT * 4;                                  // 4 MB
    float* Hpart  = (float*)(ws + off);
    off += (size_t)2 * NH * NN * FOUT * 4;                              // 8.4 MB
    float* lpartP = (float*)(ws + off);
    off += (size_t)2 * NH * NN * 4;                                     // 128 KB

    pack_bits<<<NN, 256, 0, stream>>>(A, Abits);
    gat_prep<<<dim3(128, 4), 256, 0, stream>>>(X, W, b, att, HbfT, Hrow,
                                               s_buf, d_buf,
                                               es_buf, es2_buf, ed_buf, ed2_buf);
    gat_main<<<512, 256, 0, stream>>>((const unsigned*)Abits, HbfT,
                                      es_buf, es2_buf, ed_buf, ed2_buf,
                                      Hpart, lpartP);
    gat_fin<<<256, 256, 0, stream>>>(Hpart, Hrow, lpartP, s_buf, d_buf, out);
}

// Round 10
// 184.725 us; speedup vs baseline: 1.1422x; 1.1422x over previous
//
#include <hip/hip_runtime.h>
#include <hip/hip_bf16.h>

// GAT layer: N=4096, F_IN=128, F_OUT=64, HEADS=4.
// R10: R9 traffic structure + 4x grid (the R9 regression was grid-starved
// occupancy: 512 blocks = 2/CU = 20%).
//  - cg split 8: block = 1 head x 64 rows x 512 cols (4x 128-col LDS chunks);
//    grid 2048 = 8 blocks/CU = 32 waves/CU.
//  - XCD clustering: grp=id&31, cg=grp&7 -> id%8 == cg, so each XCD owns one
//    512-col slice (HbfT+Abits ~0.5 MB/XCD, L2-resident).
//  - Hpart 8 slices (33.5 MB) via nontemporal stores; gat_fin sums 8.
// Kernels: pack_bits -> gat_prep -> gat_main -> gat_fin.

#define NN 4096
#define FIN 128
#define FOUT 64
#define NH 4

typedef __attribute__((ext_vector_type(8))) short bf16x8;
typedef __attribute__((ext_vector_type(4))) float f32x4;
typedef __attribute__((ext_vector_type(4))) unsigned int u32x4;

__device__ __forceinline__ unsigned short f32_bf16(float f) {
    unsigned u = __builtin_bit_cast(unsigned, f);
    u += 0x7fffu + ((u >> 16) & 1u);          // round-to-nearest-even
    return (unsigned short)(u >> 16);
}

// ---------------- Kernel 0: pack A (int32 0/1) into bitmask ----------------
__global__ __launch_bounds__(256) void pack_bits(
    const int* __restrict__ A, unsigned long long* __restrict__ Abits)
{
    const int row  = blockIdx.x;
    const int lane = threadIdx.x & 63;
    const int wv   = threadIdx.x >> 6;
    const int* arow = A + (size_t)row * NN;
    #pragma unroll 4
    for (int c = 0; c < 16; ++c) {
        const int col = c * 256 + wv * 64 + lane;
        unsigned long long m = __ballot(__builtin_nontemporal_load(&arow[col]) > 0);
        if (lane == 0) Abits[(size_t)row * 64 + c * 4 + wv] = m;
    }
}

// ---------------- Kernel 1: prep ----------------
__global__ __launch_bounds__(256) void gat_prep(
    const float* __restrict__ X, const float* __restrict__ W,
    const float* __restrict__ b, const float* __restrict__ att,
    unsigned short* __restrict__ HbfT, float* __restrict__ Hrow,
    float* __restrict__ s_out, float* __restrict__ d_out,
    float* __restrict__ es_g, float* __restrict__ es2_g,
    float* __restrict__ ed_g, float* __restrict__ ed2_g)
{
    const int rb = blockIdx.x;           // 0..127
    const int h  = blockIdx.y;           // 0..3
    const int n0 = rb * 32;
    const int t  = threadIdx.x;          // 0..255

    __shared__ float Xl[32][132];
    __shared__ float Wt[128][68];

    for (int g = t; g < 32 * 32; g += 256) {
        int row = g >> 5, c4 = g & 31;
        float4 v = *(const float4*)&X[(size_t)(n0 + row) * FIN + c4 * 4];
        *(float4*)&Xl[row][c4 * 4] = v;
    }
    for (int g = t; g < 64 * 32; g += 256) {
        int o = g >> 5, c4 = g & 31;
        float4 v = *(const float4*)&W[((size_t)h * FOUT + o) * FIN + c4 * 4];
        Wt[c4 * 4 + 0][o] = v.x; Wt[c4 * 4 + 1][o] = v.y;
        Wt[c4 * 4 + 2][o] = v.z; Wt[c4 * 4 + 3][o] = v.w;
    }
    __syncthreads();

    const int rg = t >> 4;               // rows rg*2 .. rg*2+1
    const int og = t & 15;               // cols og*4 .. og*4+3
    float acc[2][4] = {};

    #pragma unroll 4
    for (int f4 = 0; f4 < 32; ++f4) {
        float xv[2][4], wv[4][4];
        #pragma unroll
        for (int i = 0; i < 2; ++i) {
            float4 tmp = *(const float4*)&Xl[rg * 2 + i][f4 * 4];
            xv[i][0] = tmp.x; xv[i][1] = tmp.y; xv[i][2] = tmp.z; xv[i][3] = tmp.w;
        }
        #pragma unroll
        for (int k = 0; k < 4; ++k) {
            float4 tmp = *(const float4*)&Wt[f4 * 4 + k][og * 4];
            wv[k][0] = tmp.x; wv[k][1] = tmp.y; wv[k][2] = tmp.z; wv[k][3] = tmp.w;
        }
        #pragma unroll
        for (int i = 0; i < 2; ++i)
            #pragma unroll
            for (int k = 0; k < 4; ++k)
                #pragma unroll
                for (int jj = 0; jj < 4; ++jj)
                    acc[i][jj] = fmaf(xv[i][k], wv[k][jj], acc[i][jj]);
    }

    float bb[4], as_[4], ad_[4];
    #pragma unroll
    for (int jj = 0; jj < 4; ++jj) {
        bb[jj]  = b[h * FOUT + og * 4 + jj];
        as_[jj] = att[h * 2 * FOUT + og * 4 + jj];
        ad_[jj] = att[h * 2 * FOUT + FOUT + og * 4 + jj];
    }
    #pragma unroll
    for (int i = 0; i < 2; ++i)
        #pragma unroll
        for (int jj = 0; jj < 4; ++jj)
            acc[i][jj] += bb[jj];

    float sp[2] = {0.f, 0.f}, dp[2] = {0.f, 0.f};
    #pragma unroll
    for (int i = 0; i < 2; ++i)
        #pragma unroll
        for (int jj = 0; jj < 4; ++jj) {
            sp[i] = fmaf(acc[i][jj], as_[jj], sp[i]);
            dp[i] = fmaf(acc[i][jj], ad_[jj], dp[i]);
        }
    #pragma unroll
    for (int off = 1; off < 16; off <<= 1) {
        #pragma unroll
        for (int i = 0; i < 2; ++i) {
            sp[i] += __shfl_xor(sp[i], off);
            dp[i] += __shfl_xor(dp[i], off);
        }
    }
    if (og == 0) {
        #pragma unroll
        for (int i = 0; i < 2; ++i) {
            int nn = n0 + rg * 2 + i;
            s_out[h * NN + nn]  = sp[i];
            d_out[h * NN + nn]  = dp[i];
            es_g [h * NN + nn]  = __expf(sp[i]);
            es2_g[h * NN + nn]  = __expf(0.01f * sp[i]);
            ed_g [h * NN + nn]  = __expf(dp[i]);
            ed2_g[h * NN + nn]  = __expf(0.01f * dp[i]);
        }
    }

    #pragma unroll
    for (int i = 0; i < 2; ++i) {
        float4 v = make_float4(acc[i][0], acc[i][1], acc[i][2], acc[i][3]);
        *(float4*)&Hrow[((size_t)h * NN + n0 + rg * 2 + i) * FOUT + og * 4] = v;
    }
    #pragma unroll
    for (int jj = 0; jj < 4; ++jj) {
        int o = og * 4 + jj;
        ushort2 p;
        p.x = f32_bf16(acc[0][jj]);
        p.y = f32_bf16(acc[1][jj]);
        *(ushort2*)&HbfT[((size_t)h * FOUT + o) * NN + n0 + rg * 2] = p;
    }
}

// ---------------- Kernel 2: masked softmax-aggregate ------------------------
// 1D grid 2048, XCD-clustered: grp=id&31 -> h=grp>>3, cg=grp&7 (id%8==cg);
// bx=id>>5 (64-row tiles). Block: 1 head x 64 rows x 512 cols, 4 chunks of 128.
__global__ __launch_bounds__(256, 8) void gat_main(
    const unsigned* __restrict__ Abits, const unsigned short* __restrict__ HbfT,
    const float* __restrict__ es_g, const float* __restrict__ es2_g,
    const float* __restrict__ ed_g, const float* __restrict__ ed2_g,
    float* __restrict__ Hpart, float* __restrict__ lpartP)
{
    const int id  = blockIdx.x;          // 0..2047
    const int grp = id & 31;             // XCD-clustered group (id%8 == grp%8 == cg)
    const int h   = grp >> 3;            // head
    const int cg  = grp & 7;             // col slice: [cg*512, +512)
    const int bx  = id >> 5;             // 0..63 row tile
    const int n0  = bx * 64;
    const int tid  = threadIdx.x;
    const int w    = tid >> 6;           // wave 0..3 -> rows w*16..+16
    const int lane = tid & 63;
    const int r    = lane & 15;          // A row within subtile / C col
    const int q    = lane >> 4;          // quad
    const int qs   = q * 8;

    __shared__ unsigned short Hlds[64][128];     // 16 KB, XOR-swizzled 16B blocks
    __shared__ unsigned bits_lds[64 * 5];        // 1.25 KB (stride 5)

    const int n = n0 + w * 16 + r;
    const float es  = es_g [h * NN + n];
    const float es2 = es2_g[h * NN + n];
    const int bits_base = (w * 16 + r) * 5;

    bf16x8 ones;
    #pragma unroll
    for (int i = 0; i < 8; ++i) ones[i] = (short)0x3F80;   // bf16 1.0

    f32x4 acc0 = {0,0,0,0}, acc1 = {0,0,0,0}, acc2 = {0,0,0,0},
          acc3 = {0,0,0,0}, accl = {0,0,0,0};

    for (int ch = 0; ch < 4; ++ch) {
        const int c0 = cg * 512 + ch * 128;
        __syncthreads();                 // previous chunk fully consumed

        // ---- stage H chunk: HbfT[h][o][c0..c0+128) -> Hlds[o][.], swizzled ----
        #pragma unroll
        for (int it = 0; it < 4; ++it) {
            int flat = it * 256 + tid;           // 0..1023 (16B blocks)
            int o    = flat >> 4;                // 0..63
            int c16  = flat & 15;
            int blk  = c16 ^ (o & 15);
            *(bf16x8*)&Hlds[o][blk * 8] =
                *(const bf16x8*)&HbfT[((size_t)h * FOUT + o) * NN + c0 + c16 * 8];
        }
        // ---- stage adjacency bits: 64 rows x 4 u32 for this chunk ----
        {
            int row = tid >> 2, wd = tid & 3;
            bits_lds[row * 5 + wd] = Abits[(size_t)(n0 + row) * 128 + (c0 >> 5) + wd];
        }
        __syncthreads();

        const float* edh  = ed_g  + h * NN + c0;
        const float* ed2h = ed2_g + h * NN + c0;

        #pragma unroll
        for (int step = 0; step < 4; ++step) {
            const unsigned bits8 = bits_lds[bits_base + step] >> qs;
            const int mk = step * 32 + qs;

            const float4 e0 = *(const float4*)&edh [mk];
            const float4 e1 = *(const float4*)&edh [mk + 4];
            const float4 g0 = *(const float4*)&ed2h[mk];
            const float4 g1 = *(const float4*)&ed2h[mk + 4];
            const float edv [8] = {e0.x, e0.y, e0.z, e0.w, e1.x, e1.y, e1.z, e1.w};
            const float ed2v[8] = {g0.x, g0.y, g0.z, g0.w, g1.x, g1.y, g1.z, g1.w};

            u32x4 afu;
            #pragma unroll
            for (int p = 0; p < 4; ++p) {
                const int j0 = 2 * p, j1 = 2 * p + 1;
                float wa = (bits8 & (1u << j0))
                         ? fmaxf(es * edv[j0], es2 * ed2v[j0]) : 0.0f;
                float wb = (bits8 & (1u << j1))
                         ? fmaxf(es * edv[j1], es2 * ed2v[j1]) : 0.0f;
                __hip_bfloat162 pk = __float22bfloat162_rn(make_float2(wa, wb));
                unsigned u;
                __builtin_memcpy(&u, &pk, sizeof(u));   // v_cvt_pk path
                afu[p] = u;
            }
            const bf16x8 af = __builtin_bit_cast(bf16x8, afu);

            // B fragments from swizzled LDS ((r+16k)&15 == r for all four)
            const int mb = (step * 4 + q) ^ r;   // 16B-block index after swizzle
            const bf16x8 b0 = *(const bf16x8*)&Hlds[r     ][mb * 8];
            const bf16x8 b1 = *(const bf16x8*)&Hlds[r + 16][mb * 8];
            const bf16x8 b2 = *(const bf16x8*)&Hlds[r + 32][mb * 8];
            const bf16x8 b3 = *(const bf16x8*)&Hlds[r + 48][mb * 8];

            acc0 = __builtin_amdgcn_mfma_f32_16x16x32_bf16(af, b0,   acc0, 0, 0, 0);
            acc1 = __builtin_amdgcn_mfma_f32_16x16x32_bf16(af, b1,   acc1, 0, 0, 0);
            acc2 = __builtin_amdgcn_mfma_f32_16x16x32_bf16(af, b2,   acc2, 0, 0, 0);
            acc3 = __builtin_amdgcn_mfma_f32_16x16x32_bf16(af, b3,   acc3, 0, 0, 0);
            accl = __builtin_amdgcn_mfma_f32_16x16x32_bf16(af, ones, accl, 0, 0, 0);
        }
    }

    // ---- epilogue: nontemporal stores into this block's private slice ----
    float* hb = Hpart + ((size_t)(cg * NH + h) * NN + n0 + w * 16) * FOUT;
    #pragma unroll
    for (int reg = 0; reg < 4; ++reg) {
        const int rr = q * 4 + reg;
        __builtin_nontemporal_store(acc0[reg], &hb[rr * FOUT +  0 + r]);
        __builtin_nontemporal_store(acc1[reg], &hb[rr * FOUT + 16 + r]);
        __builtin_nontemporal_store(acc2[reg], &hb[rr * FOUT + 32 + r]);
        __builtin_nontemporal_store(acc3[reg], &hb[rr * FOUT + 48 + r]);
    }
    if (r == 0) {                        // col-0 lanes hold the 512-col row-sums
        #pragma unroll
        for (int reg = 0; reg < 4; ++reg)
            __builtin_nontemporal_store(accl[reg],
                &lpartP[(size_t)(cg * NH + h) * NN + n0 + w * 16 + q * 4 + reg]);
    }
}

// ---------------- Kernel 3: finalize ----------------
// out[n][o] = sum_h (sum_cg Hpart + w_diag*Hrow) * 0.25/(sum_cg l + w_diag)
__global__ __launch_bounds__(256) void gat_fin(
    const float* __restrict__ Hpart, const float* __restrict__ Hrow,
    const float* __restrict__ lpartP, const float* __restrict__ s_g,
    const float* __restrict__ d_g, float* __restrict__ out)
{
    const int tid = threadIdx.x;
    const int rr  = tid >> 4;
    const int c4  = tid & 15;
    const int n   = blockIdx.x * 16 + rr;
    const int o   = c4 * 4;

    float4 res = make_float4(0.f, 0.f, 0.f, 0.f);
    #pragma unroll
    for (int h = 0; h < NH; ++h) {
        float l = 0.f;
        #pragma unroll
        for (int cg = 0; cg < 8; ++cg)
            l += lpartP[(size_t)(cg * NH + h) * NN + n];
        float tt = s_g[h * NN + n] + d_g[h * NN + n];
        float wd = __expf(fmaxf(tt, 0.01f * tt));
        float inv = 0.25f / (l + wd);

        f32x4 ha = {0.f, 0.f, 0.f, 0.f};
        #pragma unroll
        for (int cg = 0; cg < 8; ++cg) {
            f32x4 hp = __builtin_nontemporal_load(
                (const f32x4*)&Hpart[((size_t)(cg * NH + h) * NN + n) * FOUT + o]);
            ha += hp;
        }
        float4 hr = *(const float4*)&Hrow[((size_t)h * NN + n) * FOUT + o];

        res.x += (ha[0] + wd * hr.x) * inv;
        res.y += (ha[1] + wd * hr.y) * inv;
        res.z += (ha[2] + wd * hr.z) * inv;
        res.w += (ha[3] + wd * hr.w) * inv;
    }
    *(float4*)&out[(size_t)n * FOUT + o] = res;
}

extern "C" void kernel_launch(void* const* d_in, const int* in_sizes, int n_in,
                              void* d_out, int out_size, void* d_ws, size_t ws_size,
                              hipStream_t stream) {
    const float* X   = (const float*)d_in[0];
    const int*   A   = (const int*)  d_in[1];
    const float* W   = (const float*)d_in[2];
    const float* b   = (const float*)d_in[3];
    const float* att = (const float*)d_in[4];
    float* out = (float*)d_out;

    char* ws = (char*)d_ws;
    unsigned short* HbfT = (unsigned short*)ws;                    // 2 MB
    size_t off = (size_t)NH * FOUT * NN * 2;
    float* s_buf   = (float*)(ws + off);  off += (size_t)NH * NN * 4;
    float* d_buf   = (float*)(ws + off);  off += (size_t)NH * NN * 4;
    float* es_buf  = (float*)(ws + off);  off += (size_t)NH * NN * 4;
    float* es2_buf = (float*)(ws + off);  off += (size_t)NH * NN * 4;
    float* ed_buf  = (float*)(ws + off);  off += (size_t)NH * NN * 4;
    float* ed2_buf = (float*)(ws + off);  off += (size_t)NH * NN * 4;
    unsigned long long* Abits = (unsigned long long*)(ws + off);
    off += (size_t)NN * 64 * 8;                                         // 2 MB
    float* Hrow   = (float*)(ws + off);
    off += (size_t)NH * NN * FOUT * 4;                                  // 4 MB
    float* Hpart  = (float*)(ws + off);
    off += (size_t)8 * NH * NN * FOUT * 4;                              // 33.5 MB
    float* lpartP = (float*)(ws + off);
    off += (size_t)8 * NH * NN * 4;                                     // 512 KB

    pack_bits<<<NN, 256, 0, stream>>>(A, Abits);
    gat_prep<<<dim3(128, 4), 256, 0, stream>>>(X, W, b, att, HbfT, Hrow,
                                               s_buf, d_buf,
                                               es_buf, es2_buf, ed_buf, ed2_buf);
    gat_main<<<2048, 256, 0, stream>>>((const unsigned*)Abits, HbfT,
                                       es_buf, es2_buf, ed_buf, ed2_buf,
                                       Hpart, lpartP);
    gat_fin<<<256, 256, 0, stream>>>(Hpart, Hrow, lpartP, s_buf, d_buf, out);
}

// Round 11
// 168.122 us; speedup vs baseline: 1.2550x; 1.0988x over previous
//
#include <hip/hip_runtime.h>
#include <hip/hip_bf16.h>

// GAT layer: N=4096, F_IN=128, F_OUT=64, HEADS=4.
// R11: R10 + (a) regular cached stores for Hpart/lpartP (NT 64B partial-line
// writes were counted/paid 2x: WRITE 66 MB for 33.5 MB of data, plus end-of-
// kernel burst drain) and (b) 512-thr blocks, 128 rows x 512 cols, grid 1024
// = 4 blocks/CU = 32 waves/CU (100% occupancy vs R10's 67%).
// XCD clustering unchanged: id%8 == cg -> each XCD owns one 512-col slice.
// Kernels: pack_bits -> gat_prep -> gat_main -> gat_fin.

#define NN 4096
#define FIN 128
#define FOUT 64
#define NH 4

typedef __attribute__((ext_vector_type(8))) short bf16x8;
typedef __attribute__((ext_vector_type(4))) float f32x4;
typedef __attribute__((ext_vector_type(4))) unsigned int u32x4;

__device__ __forceinline__ unsigned short f32_bf16(float f) {
    unsigned u = __builtin_bit_cast(unsigned, f);
    u += 0x7fffu + ((u >> 16) & 1u);          // round-to-nearest-even
    return (unsigned short)(u >> 16);
}

// ---------------- Kernel 0: pack A (int32 0/1) into bitmask ----------------
__global__ __launch_bounds__(256) void pack_bits(
    const int* __restrict__ A, unsigned long long* __restrict__ Abits)
{
    const int row  = blockIdx.x;
    const int lane = threadIdx.x & 63;
    const int wv   = threadIdx.x >> 6;
    const int* arow = A + (size_t)row * NN;
    #pragma unroll 4
    for (int c = 0; c < 16; ++c) {
        const int col = c * 256 + wv * 64 + lane;
        unsigned long long m = __ballot(__builtin_nontemporal_load(&arow[col]) > 0);
        if (lane == 0) Abits[(size_t)row * 64 + c * 4 + wv] = m;
    }
}

// ---------------- Kernel 1: prep ----------------
__global__ __launch_bounds__(256) void gat_prep(
    const float* __restrict__ X, const float* __restrict__ W,
    const float* __restrict__ b, const float* __restrict__ att,
    unsigned short* __restrict__ HbfT, float* __restrict__ Hrow,
    float* __restrict__ s_out, float* __restrict__ d_out,
    float* __restrict__ es_g, float* __restrict__ es2_g,
    float* __restrict__ ed_g, float* __restrict__ ed2_g)
{
    const int rb = blockIdx.x;           // 0..127
    const int h  = blockIdx.y;           // 0..3
    const int n0 = rb * 32;
    const int t  = threadIdx.x;          // 0..255

    __shared__ float Xl[32][132];
    __shared__ float Wt[128][68];

    for (int g = t; g < 32 * 32; g += 256) {
        int row = g >> 5, c4 = g & 31;
        float4 v = *(const float4*)&X[(size_t)(n0 + row) * FIN + c4 * 4];
        *(float4*)&Xl[row][c4 * 4] = v;
    }
    for (int g = t; g < 64 * 32; g += 256) {
        int o = g >> 5, c4 = g & 31;
        float4 v = *(const float4*)&W[((size_t)h * FOUT + o) * FIN + c4 * 4];
        Wt[c4 * 4 + 0][o] = v.x; Wt[c4 * 4 + 1][o] = v.y;
        Wt[c4 * 4 + 2][o] = v.z; Wt[c4 * 4 + 3][o] = v.w;
    }
    __syncthreads();

    const int rg = t >> 4;               // rows rg*2 .. rg*2+1
    const int og = t & 15;               // cols og*4 .. og*4+3
    float acc[2][4] = {};

    #pragma unroll 4
    for (int f4 = 0; f4 < 32; ++f4) {
        float xv[2][4], wv[4][4];
        #pragma unroll
        for (int i = 0; i < 2; ++i) {
            float4 tmp = *(const float4*)&Xl[rg * 2 + i][f4 * 4];
            xv[i][0] = tmp.x; xv[i][1] = tmp.y; xv[i][2] = tmp.z; xv[i][3] = tmp.w;
        }
        #pragma unroll
        for (int k = 0; k < 4; ++k) {
            float4 tmp = *(const float4*)&Wt[f4 * 4 + k][og * 4];
            wv[k][0] = tmp.x; wv[k][1] = tmp.y; wv[k][2] = tmp.z; wv[k][3] = tmp.w;
        }
        #pragma unroll
        for (int i = 0; i < 2; ++i)
            #pragma unroll
            for (int k = 0; k < 4; ++k)
                #pragma unroll
                for (int jj = 0; jj < 4; ++jj)
                    acc[i][jj] = fmaf(xv[i][k], wv[k][jj], acc[i][jj]);
    }

    float bb[4], as_[4], ad_[4];
    #pragma unroll
    for (int jj = 0; jj < 4; ++jj) {
        bb[jj]  = b[h * FOUT + og * 4 + jj];
        as_[jj] = att[h * 2 * FOUT + og * 4 + jj];
        ad_[jj] = att[h * 2 * FOUT + FOUT + og * 4 + jj];
    }
    #pragma unroll
    for (int i = 0; i < 2; ++i)
        #pragma unroll
        for (int jj = 0; jj < 4; ++jj)
            acc[i][jj] += bb[jj];

    float sp[2] = {0.f, 0.f}, dp[2] = {0.f, 0.f};
    #pragma unroll
    for (int i = 0; i < 2; ++i)
        #pragma unroll
        for (int jj = 0; jj < 4; ++jj) {
            sp[i] = fmaf(acc[i][jj], as_[jj], sp[i]);
            dp[i] = fmaf(acc[i][jj], ad_[jj], dp[i]);
        }
    #pragma unroll
    for (int off = 1; off < 16; off <<= 1) {
        #pragma unroll
        for (int i = 0; i < 2; ++i) {
            sp[i] += __shfl_xor(sp[i], off);
            dp[i] += __shfl_xor(dp[i], off);
        }
    }
    if (og == 0) {
        #pragma unroll
        for (int i = 0; i < 2; ++i) {
            int nn = n0 + rg * 2 + i;
            s_out[h * NN + nn]  = sp[i];
            d_out[h * NN + nn]  = dp[i];
            es_g [h * NN + nn]  = __expf(sp[i]);
            es2_g[h * NN + nn]  = __expf(0.01f * sp[i]);
            ed_g [h * NN + nn]  = __expf(dp[i]);
            ed2_g[h * NN + nn]  = __expf(0.01f * dp[i]);
        }
    }

    #pragma unroll
    for (int i = 0; i < 2; ++i) {
        float4 v = make_float4(acc[i][0], acc[i][1], acc[i][2], acc[i][3]);
        *(float4*)&Hrow[((size_t)h * NN + n0 + rg * 2 + i) * FOUT + og * 4] = v;
    }
    #pragma unroll
    for (int jj = 0; jj < 4; ++jj) {
        int o = og * 4 + jj;
        ushort2 p;
        p.x = f32_bf16(acc[0][jj]);
        p.y = f32_bf16(acc[1][jj]);
        *(ushort2*)&HbfT[((size_t)h * FOUT + o) * NN + n0 + rg * 2] = p;
    }
}

// ---------------- Kernel 2: masked softmax-aggregate ------------------------
// 1D grid 1024 x 512 thr (8 waves), XCD-clustered: grp=id&31 -> h=grp>>3,
// cg=grp&7 (id%8==cg); bx=id>>5 (0..31, 128-row tiles).
// Block: 1 head x 128 rows x 512 cols, 4 chunks of 128 cols.
__global__ __launch_bounds__(512, 8) void gat_main(
    const unsigned* __restrict__ Abits, const unsigned short* __restrict__ HbfT,
    const float* __restrict__ es_g, const float* __restrict__ es2_g,
    const float* __restrict__ ed_g, const float* __restrict__ ed2_g,
    float* __restrict__ Hpart, float* __restrict__ lpartP)
{
    const int id  = blockIdx.x;          // 0..1023
    const int grp = id & 31;             // XCD-clustered group (id%8 == cg)
    const int h   = grp >> 3;            // head
    const int cg  = grp & 7;             // col slice: [cg*512, +512)
    const int bx  = id >> 5;             // 0..31 row tile (128 rows)
    const int n0  = bx * 128;
    const int tid  = threadIdx.x;        // 0..511
    const int w    = tid >> 6;           // wave 0..7 -> rows w*16..+16
    const int lane = tid & 63;
    const int r    = lane & 15;          // A row within subtile / C col
    const int q    = lane >> 4;          // quad
    const int qs   = q * 8;

    __shared__ unsigned short Hlds[64][128];     // 16 KB, XOR-swizzled 16B blocks
    __shared__ unsigned bits_lds[128 * 5];       // 2.5 KB (stride 5)

    const int n = n0 + w * 16 + r;
    const float es  = es_g [h * NN + n];
    const float es2 = es2_g[h * NN + n];
    const int bits_base = (w * 16 + r) * 5;

    bf16x8 ones;
    #pragma unroll
    for (int i = 0; i < 8; ++i) ones[i] = (short)0x3F80;   // bf16 1.0

    f32x4 acc0 = {0,0,0,0}, acc1 = {0,0,0,0}, acc2 = {0,0,0,0},
          acc3 = {0,0,0,0}, accl = {0,0,0,0};

    for (int ch = 0; ch < 4; ++ch) {
        const int c0 = cg * 512 + ch * 128;
        __syncthreads();                 // previous chunk fully consumed

        // ---- stage H chunk: HbfT[h][o][c0..c0+128) -> Hlds[o][.], swizzled ----
        #pragma unroll
        for (int it = 0; it < 2; ++it) {
            int flat = it * 512 + tid;           // 0..1023 (16B blocks)
            int o    = flat >> 4;                // 0..63
            int c16  = flat & 15;
            int blk  = c16 ^ (o & 15);
            *(bf16x8*)&Hlds[o][blk * 8] =
                *(const bf16x8*)&HbfT[((size_t)h * FOUT + o) * NN + c0 + c16 * 8];
        }
        // ---- stage adjacency bits: 128 rows x 4 u32 for this chunk ----
        {
            int row = tid >> 2, wd = tid & 3;    // 512 threads cover 128x4
            bits_lds[row * 5 + wd] = Abits[(size_t)(n0 + row) * 128 + (c0 >> 5) + wd];
        }
        __syncthreads();

        const float* edh  = ed_g  + h * NN + c0;
        const float* ed2h = ed2_g + h * NN + c0;

        #pragma unroll
        for (int step = 0; step < 4; ++step) {
            const unsigned bits8 = bits_lds[bits_base + step] >> qs;
            const int mk = step * 32 + qs;

            const float4 e0 = *(const float4*)&edh [mk];
            const float4 e1 = *(const float4*)&edh [mk + 4];
            const float4 g0 = *(const float4*)&ed2h[mk];
            const float4 g1 = *(const float4*)&ed2h[mk + 4];
            const float edv [8] = {e0.x, e0.y, e0.z, e0.w, e1.x, e1.y, e1.z, e1.w};
            const float ed2v[8] = {g0.x, g0.y, g0.z, g0.w, g1.x, g1.y, g1.z, g1.w};

            u32x4 afu;
            #pragma unroll
            for (int p = 0; p < 4; ++p) {
                const int j0 = 2 * p, j1 = 2 * p + 1;
                float wa = (bits8 & (1u << j0))
                         ? fmaxf(es * edv[j0], es2 * ed2v[j0]) : 0.0f;
                float wb = (bits8 & (1u << j1))
                         ? fmaxf(es * edv[j1], es2 * ed2v[j1]) : 0.0f;
                __hip_bfloat162 pk = __float22bfloat162_rn(make_float2(wa, wb));
                unsigned u;
                __builtin_memcpy(&u, &pk, sizeof(u));   // v_cvt_pk path
                afu[p] = u;
            }
            const bf16x8 af = __builtin_bit_cast(bf16x8, afu);

            // B fragments from swizzled LDS ((r+16k)&15 == r for all four)
            const int mb = (step * 4 + q) ^ r;   // 16B-block index after swizzle
            const bf16x8 b0 = *(const bf16x8*)&Hlds[r     ][mb * 8];
            const bf16x8 b1 = *(const bf16x8*)&Hlds[r + 16][mb * 8];
            const bf16x8 b2 = *(const bf16x8*)&Hlds[r + 32][mb * 8];
            const bf16x8 b3 = *(const bf16x8*)&Hlds[r + 48][mb * 8];

            acc0 = __builtin_amdgcn_mfma_f32_16x16x32_bf16(af, b0,   acc0, 0, 0, 0);
            acc1 = __builtin_amdgcn_mfma_f32_16x16x32_bf16(af, b1,   acc1, 0, 0, 0);
            acc2 = __builtin_amdgcn_mfma_f32_16x16x32_bf16(af, b2,   acc2, 0, 0, 0);
            acc3 = __builtin_amdgcn_mfma_f32_16x16x32_bf16(af, b3,   acc3, 0, 0, 0);
            accl = __builtin_amdgcn_mfma_f32_16x16x32_bf16(af, ones, accl, 0, 0, 0);
        }
    }

    // ---- epilogue: regular cached stores (L2 merges 64B halves) ----
    float* hb = Hpart + ((size_t)(cg * NH + h) * NN + n0 + w * 16) * FOUT;
    #pragma unroll
    for (int reg = 0; reg < 4; ++reg) {
        const int rr = q * 4 + reg;
        hb[rr * FOUT +  0 + r] = acc0[reg];
        hb[rr * FOUT + 16 + r] = acc1[reg];
        hb[rr * FOUT + 32 + r] = acc2[reg];
        hb[rr * FOUT + 48 + r] = acc3[reg];
    }
    if (r == 0) {                        // col-0 lanes hold the 512-col row-sums
        #pragma unroll
        for (int reg = 0; reg < 4; ++reg)
            lpartP[(size_t)(cg * NH + h) * NN + n0 + w * 16 + q * 4 + reg] = accl[reg];
    }
}

// ---------------- Kernel 3: finalize ----------------
// out[n][o] = sum_h (sum_cg Hpart + w_diag*Hrow) * 0.25/(sum_cg l + w_diag)
__global__ __launch_bounds__(256) void gat_fin(
    const float* __restrict__ Hpart, const float* __restrict__ Hrow,
    const float* __restrict__ lpartP, const float* __restrict__ s_g,
    const float* __restrict__ d_g, float* __restrict__ out)
{
    const int tid = threadIdx.x;
    const int rr  = tid >> 4;
    const int c4  = tid & 15;
    const int n   = blockIdx.x * 16 + rr;
    const int o   = c4 * 4;

    float4 res = make_float4(0.f, 0.f, 0.f, 0.f);
    #pragma unroll
    for (int h = 0; h < NH; ++h) {
        float l = 0.f;
        #pragma unroll
        for (int cg = 0; cg < 8; ++cg)
            l += lpartP[(size_t)(cg * NH + h) * NN + n];
        float tt = s_g[h * NN + n] + d_g[h * NN + n];
        float wd = __expf(fmaxf(tt, 0.01f * tt));
        float inv = 0.25f / (l + wd);

        f32x4 ha = {0.f, 0.f, 0.f, 0.f};
        #pragma unroll
        for (int cg = 0; cg < 8; ++cg) {
            f32x4 hp = __builtin_nontemporal_load(
                (const f32x4*)&Hpart[((size_t)(cg * NH + h) * NN + n) * FOUT + o]);
            ha += hp;
        }
        float4 hr = *(const float4*)&Hrow[((size_t)h * NN + n) * FOUT + o];

        res.x += (ha[0] + wd * hr.x) * inv;
        res.y += (ha[1] + wd * hr.y) * inv;
        res.z += (ha[2] + wd * hr.z) * inv;
        res.w += (ha[3] + wd * hr.w) * inv;
    }
    *(float4*)&out[(size_t)n * FOUT + o] = res;
}

extern "C" void kernel_launch(void* const* d_in, const int* in_sizes, int n_in,
                              void* d_out, int out_size, void* d_ws, size_t ws_size,
                              hipStream_t stream) {
    const float* X   = (const float*)d_in[0];
    const int*   A   = (const int*)  d_in[1];
    const float* W   = (const float*)d_in[2];
    const float* b   = (const float*)d_in[3];
    const float* att = (const float*)d_in[4];
    float* out = (float*)d_out;

    char* ws = (char*)d_ws;
    unsigned short* HbfT = (unsigned short*)ws;                    // 2 MB
    size_t off = (size_t)NH * FOUT * NN * 2;
    float* s_buf   = (float*)(ws + off);  off += (size_t)NH * NN * 4;
    float* d_buf   = (float*)(ws + off);  off += (size_t)NH * NN * 4;
    float* es_buf  = (float*)(ws + off);  off += (size_t)NH * NN * 4;
    float* es2_buf = (float*)(ws + off);  off += (size_t)NH * NN * 4;
    float* ed_buf  = (float*)(ws + off);  off += (size_t)NH * NN * 4;
    float* ed2_buf = (float*)(ws + off);  off += (size_t)NH * NN * 4;
    unsigned long long* Abits = (unsigned long long*)(ws + off);
    off += (size_t)NN * 64 * 8;                                         // 2 MB
    float* Hrow   = (float*)(ws + off);
    off += (size_t)NH * NN * FOUT * 4;                                  // 4 MB
    float* Hpart  = (float*)(ws + off);
    off += (size_t)8 * NH * NN * FOUT * 4;                              // 33.5 MB
    float* lpartP = (float*)(ws + off);
    off += (size_t)8 * NH * NN * 4;                                     // 512 KB

    pack_bits<<<NN, 256, 0, stream>>>(A, Abits);
    gat_prep<<<dim3(128, 4), 256, 0, stream>>>(X, W, b, att, HbfT, Hrow,
                                               s_buf, d_buf,
                                               es_buf, es2_buf, ed_buf, ed2_buf);
    gat_main<<<1024, 512, 0, stream>>>((const unsigned*)Abits, HbfT,
                                       es_buf, es2_buf, ed_buf, ed2_buf,
                                       Hpart, lpartP);
    gat_fin<<<256, 256, 0, stream>>>(Hpart, Hrow, lpartP, s_buf, d_buf, out);
}